// Round 14
// baseline (170.748 us; speedup 1.0000x reference)
//
#include <hip/hip_runtime.h>

#define DEVI __device__ __forceinline__

typedef __bf16 v8bf __attribute__((ext_vector_type(8)));
typedef float  v4f  __attribute__((ext_vector_type(4)));
typedef short  v4s  __attribute__((ext_vector_type(4)));

DEVI unsigned short f2bf(float f) {
  unsigned u = __builtin_bit_cast(unsigned, f);
  u += 0x7fffu + ((u >> 16) & 1u);
  return (unsigned short)(u >> 16);
}
DEVI v4f MFMA32(v8bf a, v8bf b, v4f c) {
  return __builtin_amdgcn_mfma_f32_16x16x32_bf16(a, b, c, 0, 0, 0);
}
DEVI v8bf ldfrag(const unsigned short* p) {
  return __builtin_bit_cast(v8bf, *(const uint4*)p);
}
DEVI v4s ld4s(const unsigned short* p) {
  return __builtin_bit_cast(v4s, *(const uint2*)p);
}
// pack two floats -> two bf16 in one dword (round-half-up + v_perm)
DEVI unsigned pkbf(float lo, float hi) {
  unsigned a = __builtin_bit_cast(unsigned, hi) + 0x8000u;
  unsigned b = __builtin_bit_cast(unsigned, lo) + 0x8000u;
  return __builtin_amdgcn_perm(a, b, 0x07060302u);
}
DEVI float lo2f(unsigned u) { return __builtin_bit_cast(float, u << 16); }
DEVI float hi2f(unsigned u) { return __builtin_bit_cast(float, u & 0xffff0000u); }

// explicit drain of outstanding global_load_lds DMA before each barrier.
// The backend's waitcnt pass only inserts vmcnt(0) before s_barrier when it
// sees an intra-wave dependency; relying on it implicitly raced in round 4.
DEVI void drain_vmem() { asm volatile("s_waitcnt vmcnt(0)" ::: "memory"); }

#if __has_builtin(__builtin_amdgcn_exp2f)
DEVI float fexp2(float x) { return __builtin_amdgcn_exp2f(x); }
#else
DEVI float fexp2(float x) { return exp2f(x); }
#endif

#if __has_builtin(__builtin_amdgcn_mfma_f32_16x16x16bf16_1k)
#define HAVE_MFMA16 1
DEVI v4f MFMA16(v4s a, v4s b, v4f c) {
  return __builtin_amdgcn_mfma_f32_16x16x16bf16_1k(a, b, c, 0, 0, 0);
}
#else
#define HAVE_MFMA16 0
#endif

// async global->LDS, 16B per lane; per-lane global addresses pre-apply the
// XOR swizzle (LDS side must stay contiguous).
#if __has_builtin(__builtin_amdgcn_global_load_lds)
DEVI void g2l(const unsigned short* g, unsigned short* l) {
  __builtin_amdgcn_global_load_lds(
      (const __attribute__((address_space(1))) unsigned int*)g,
      (__attribute__((address_space(3))) unsigned int*)l, 16, 0, 0);
}
#else
DEVI void g2l(const unsigned short* g, unsigned short* l) {
  *(uint4*)((char*)l + (threadIdx.x & 63) * 16) = *(const uint4*)g;
}
#endif

// ---------------------------------------------------------------------------
// fp32 -> bf16 conversion of X (4,2,1024,512) and Wq/Wk/Wv/Wo (512x512 each).
// ---------------------------------------------------------------------------
__global__ __launch_bounds__(256) void convert_kernel(
    const float* __restrict__ X, const float* __restrict__ Wq,
    const float* __restrict__ Wk, const float* __restrict__ Wv,
    const float* __restrict__ Wo, unsigned short* __restrict__ dst)
{
  int t = blockIdx.x * 256 + threadIdx.x;
  int idx = t * 4;
  const float* src;
  if (idx < 4194304) {
    src = X + idx;
  } else {
    int u = idx - 4194304;
    int w = u >> 18;
    const float* W = (w == 0) ? Wq : (w == 1) ? Wk : (w == 2) ? Wv : Wo;
    src = W + (u & 262143);
  }
  float4 f = *(const float4*)src;
  uint2 o;
  o.x = pkbf(f.x, f.y);
  o.y = pkbf(f.z, f.w);
  *(uint2*)&dst[idx] = o;
}

// ---------------------------------------------------------------------------
// C[m][n] = sum_k A[m][k]*W[n][k] + bias[n]   (BT GEMM, M=8192 N=512 K=512)
// BMx128 tile, 4 waves, global_load_lds staging, XOR-swizzled LDS.
// DOUBLE-BUFFERED: one barrier per k-step; tile kt+1 is issued right after
// the barrier and has the whole compute(kt) phase in flight.  An EXPLICIT
// s_waitcnt vmcnt(0) before each barrier enforces the DMA->barrier->ds_read
// protocol (the backend omits it after full unroll -> round-4 race).
// XCD-chunked swizzle (T1), nwg%8==0 for both grids.
// OUTM=0 bf16 out.  z==2 (V transposed into VT) routes the output tile
// through LDS so VT global stores are 4 full rows x 256 B per instruction.
// OUTM=1 fp32 out.
// ---------------------------------------------------------------------------
template<int OUTM, int BM>
__global__ __launch_bounds__(256) void gemm_bt(
    const unsigned short* __restrict__ A,
    const unsigned short* __restrict__ W0, const unsigned short* __restrict__ W1,
    const unsigned short* __restrict__ W2,
    const float* __restrict__ b0, const float* __restrict__ b1, const float* __restrict__ b2,
    void* __restrict__ C0, void* __restrict__ C1, void* __restrict__ C2)
{
  const int K = 512, N = 512;
  const int MI = BM / 32;
  const int PER = (BM / 8 + 16) / 4;          // g2l chunks per wave
  __shared__ unsigned short sAB[2][(BM + 128) * 64];

  // XCD-chunked blockIdx swizzle (bijective; nwg = 768 or 512, both %8==0)
  const int gx = gridDim.x, gy = gridDim.y;
  const int nwg = gx * gy * gridDim.z;
  const int lin = (blockIdx.z * gy + blockIdx.y) * gx + blockIdx.x;
  const int wsw = (lin & 7) * (nwg >> 3) + (lin >> 3);
  const int bx = wsw % gx, by = (wsw / gx) % gy;
  const int z = wsw / (gx * gy);

  const unsigned short* W = (z == 0) ? W0 : (z == 1) ? W1 : W2;
  const float* bias = (z == 0) ? b0 : (z == 1) ? b1 : b2;
  void* C = (z == 0) ? C0 : (z == 1) ? C1 : C2;

  const int tid = threadIdx.x;
  const int lane = tid & 63, wave = tid >> 6;
  const int l15 = lane & 15, quad = lane >> 4, swl = l15 & 7;
  const int lrow = lane >> 3;
  const int lc8 = ((lane & 7) ^ (lrow & 7)) * 8;
  const int wm = (wave >> 1) * (BM / 2), wn = (wave & 1) * 64;
  const int mbase = by * BM, nbase = bx * 128;

  const unsigned short* gsrc[PER];
  int loff[PER];
#pragma unroll
  for (int t = 0; t < PER; t++) {
    int c = wave * PER + t;
    loff[t] = c * 512;
    if (c < BM / 8) gsrc[t] = A + (size_t)(mbase + c * 8 + lrow) * K + lc8;
    else            gsrc[t] = W + (size_t)(nbase + (c - BM / 8) * 8 + lrow) * K + lc8;
  }

  v4f acc[MI][4] = {};

#pragma unroll
  for (int t = 0; t < PER; t++) g2l(gsrc[t], &sAB[0][loff[t]]);   // tile 0

  for (int kt = 0; kt < K / 64; kt++) {
    drain_vmem();                             // tile kt DMA landed (explicit!)
    __syncthreads();                          // all waves' tile kt visible
    if (kt < K / 64 - 1) {
#pragma unroll
      for (int t = 0; t < PER; t++)
        g2l(gsrc[t] + (kt + 1) * 64, &sAB[(kt + 1) & 1][loff[t]]);
    }
    const int bu = kt & 1;
#pragma unroll
    for (int s = 0; s < 2; s++) {
      v8bf af[MI], bf[4];
#pragma unroll
      for (int i = 0; i < MI; i++)
        af[i] = ldfrag(&sAB[bu][(wm + i * 16 + l15) * 64 + ((s * 4 + quad) ^ swl) * 8]);
#pragma unroll
      for (int j = 0; j < 4; j++)
        bf[j] = ldfrag(&sAB[bu][(BM + wn + j * 16 + l15) * 64 + ((s * 4 + quad) ^ swl) * 8]);
#pragma unroll
      for (int i = 0; i < MI; i++)
#pragma unroll
        for (int j = 0; j < 4; j++)
          acc[i][j] = MFMA32(af[i], bf[j], acc[i][j]);
    }
  }

  if (OUTM == 0 && BM == 128 && z == 2) {
    // ---- VT epilogue via LDS transpose (coalesced 256 B row segments) ----
    const int TP = 136;                       // padded t'-pitch (16B-aligned)
    unsigned short* T = &sAB[0][0];           // 128*136*2 B = 34 KB, sAB dead
    __syncthreads();                          // all K-loop LDS reads done
#pragma unroll
    for (int i = 0; i < MI; i++)
#pragma unroll
      for (int j = 0; j < 4; j++) {
        int tp = wm + i * 16 + quad * 4;      // t' = row0 - mbase
        int c  = wn + j * 16 + l15;           // hd-col index = col - nbase
        int col = nbase + c;
        float v[4];
#pragma unroll
        for (int r = 0; r < 4; r++) v[r] = acc[i][j][r] + bias[col];
        uint2 o;
        o.x = pkbf(v[0], v[1]);
        o.y = pkbf(v[2], v[3]);
        *(uint2*)&T[c * TP + tp] = o;
      }
    __syncthreads();                          // tile staged
    const int bs = mbase >> 10, tbase = mbase & 1023;
    const int hh0 = nbase >> 6;
#pragma unroll
    for (int it = 0; it < 8; it++) {
      int rh = wave * 32 + it * 4 + quad;     // c-index = VT row within tile
      uint4 d = *(const uint4*)&T[rh * TP + l15 * 8];
      int rowIdx = (bs * 8 + hh0 + (rh >> 6)) * 64 + (rh & 63);
      *(uint4*)&((unsigned short*)C)[(size_t)rowIdx * 1024 + tbase + l15 * 8] = d;
    }
  } else {
#pragma unroll
    for (int i = 0; i < MI; i++)
#pragma unroll
      for (int j = 0; j < 4; j++) {
        int row0 = mbase + wm + i * 16 + quad * 4;
        int col = nbase + wn + j * 16 + l15;
        float v[4];
#pragma unroll
        for (int r = 0; r < 4; r++) v[r] = acc[i][j][r] + bias[col];
        if (OUTM == 1) {
#pragma unroll
          for (int r = 0; r < 4; r++) ((float*)C)[(size_t)(row0 + r) * N + col] = v[r];
        } else if (z == 2) {
          int bs = row0 >> 10, t0 = row0 & 1023;
          int hh = col >> 6, hd = col & 63;
          uint2 o;
          o.x = pkbf(v[0], v[1]);
          o.y = pkbf(v[2], v[3]);
          *(uint2*)&((unsigned short*)C)[(size_t)((bs * 8 + hh) * 64 + hd) * 1024 + t0] = o;
        } else {
#pragma unroll
          for (int r = 0; r < 4; r++)
            ((unsigned short*)C)[(size_t)(row0 + r) * N + col] = f2bf(v[r]);
        }
      }
  }
}

// ---------------------------------------------------------------------------
// attn pass A: l-sums only.  8-WAVE QT-MERGE (same staging-dedup mechanism
// proven on attn_b in round 13): 512 threads own 128 q-rows (wave keeps its
// 16 rows -> per-wave work per barrier unchanged).  Grid 512:
// bid&31 = (b,h) pair, (bid>>5)&7 = qt-pair, bid>>8 = k-half.
// LDS = sK only (32 KB) -> 2 blocks/CU = 16 waves/CU (same waves as before)
// but HALF the independent staging streams per CU.  16 K chunks over 8
// waves = 2/wave.  s_setprio(1) around the MFMA cluster (T5).
// ---------------------------------------------------------------------------
__global__ __launch_bounds__(512, 4) void attn_a(
    const unsigned short* __restrict__ Qg, const unsigned short* __restrict__ Kg,
    float* __restrict__ Lws)
{
  __shared__ unsigned short sK[2][2][64][64];   // [buf][stream]

  const int pair = blockIdx.x & 31;           // h = pair&7 -> XCD L2 affinity
  const int b = pair >> 3, h = pair & 7;
  const int qt2 = (blockIdx.x >> 5) & 7;      // qt-pair (128 q-rows)
  const int kh = blockIdx.x >> 8;             // k-half 0/1
  const int tid = threadIdx.x;
  const int lane = tid & 63, wave = tid >> 6; // 0..7
  const int l15 = lane & 15, quad = lane >> 4, swl = l15 & 7;
  const int lrow = lane >> 3;
  const int lc8 = ((lane & 7) ^ (lrow & 7)) * 8;
  const int qbase = qt2 * 128 + wave * 16;
  const float S2 = 0.125f * 1.44269504f;      // scale * log2(e)

  const unsigned short* kgp[2];
#pragma unroll
  for (int st = 0; st < 2; st++)
    kgp[st] = Kg + (size_t)((b * 2 + st) * 1024) * 512 + h * 64;

  // Q fragments, both directions
  v8bf qf[2][2];
#pragma unroll
  for (int d = 0; d < 2; d++)
#pragma unroll
    for (int s = 0; s < 2; s++) {
      int qrow = (b * 2 + d) * 1024 + qbase + l15;
      qf[d][s] = ldfrag(&Qg[(size_t)qrow * 512 + h * 64 + s * 32 + quad * 8]);
    }

  const unsigned short* gA[2];
  unsigned short* lA[2][2];
#pragma unroll
  for (int t = 0; t < 2; t++) {
    int c = wave * 2 + t;                     // 16 K chunks over 8 waves
    gA[t] = kgp[c >> 3] + (size_t)((c & 7) * 8 + lrow) * 512 + lc8
            + (size_t)kh * 262144;            // k-half base (8 tiles)
    lA[0][t] = &sK[0][c >> 3][(c & 7) * 8][0];
    lA[1][t] = &sK[1][c >> 3][(c & 7) * 8][0];
  }

  float lacc[2] = {0.f, 0.f};
#pragma unroll
  for (int t = 0; t < 2; t++) g2l(gA[t], lA[0][t]);      // tile 0

  for (int kt = 0; kt < 8; kt++) {
    drain_vmem();                             // tile kt DMA landed
    __syncthreads();
    if (kt < 7) {
#pragma unroll
      for (int t = 0; t < 2; t++)
        g2l(gA[t] + (size_t)(kt + 1) * 32768, lA[(kt + 1) & 1][t]);
    }
    const int bu = kt & 1;
    v4f acc[2][4] = {};
    __builtin_amdgcn_s_setprio(1);
#pragma unroll
    for (int s = 0; s < 2; s++)
#pragma unroll
      for (int d = 0; d < 2; d++)
#pragma unroll
        for (int j = 0; j < 4; j++) {
          v8bf kf = ldfrag(&sK[bu][1 - d][j * 16 + l15][((s * 4 + quad) ^ swl) * 8]);
          acc[d][j] = MFMA32(kf, qf[d][s], acc[d][j]);
        }
    __builtin_amdgcn_s_setprio(0);
#pragma unroll
    for (int d = 0; d < 2; d++)
#pragma unroll
      for (int j = 0; j < 4; j++)
#pragma unroll
        for (int r = 0; r < 4; r++)
          lacc[d] += fexp2(acc[d][j][r] * S2);
  }

  float lv[2];
#pragma unroll
  for (int d = 0; d < 2; d++) {
    float v = lacc[d];
    v += __shfl_xor(v, 16);
    v += __shfl_xor(v, 32);
    lv[d] = v;                                // partial row-sum (linear domain)
  }
  if (quad == 0) {
#pragma unroll
    for (int d = 0; d < 2; d++) {
      int qrow = (b * 2 + d) * 1024 + qbase + l15;
      Lws[(size_t)qrow * 2 + kh] = lv[d];
    }
  }
}

// ---------------------------------------------------------------------------
// attn pass B: combine + PV.  8-WAVE QT-MERGE (round 13, verified): 512
// threads, block owns 128 q-rows, grid 256 = 1 block/CU; one staged K/V tile
// serves 8 waves.  Sync skeleton: drain -> barrier -> issue g2l(kt+1) ->
// compute(kt).  Staging: 32 chunks over 8 waves = 4/wave.  s_setprio (T5).
// ---------------------------------------------------------------------------
__global__ __launch_bounds__(512, 2) void attn_b(
    const unsigned short* __restrict__ Qg, const unsigned short* __restrict__ Kg,
    const unsigned short* __restrict__ VTg, const float* __restrict__ Lws,
    unsigned short* __restrict__ Hc)
{
  __shared__ unsigned short sK[2][2][64][64];   // [buf][stream]
  __shared__ unsigned short sV[2][2][64][64];

  const int pair = blockIdx.x & 31;           // h = pair&7 -> XCD L2 affinity
  const int b = pair >> 3, h = pair & 7;
  const int qt = blockIdx.x >> 5;             // 0..7 (128 q-rows per block)
  const int tid = threadIdx.x;
  const int lane = tid & 63, wave = tid >> 6; // 0..7
  const int l15 = lane & 15, quad = lane >> 4, swl = l15 & 7;
  const int lrow = lane >> 3;
  const int lc8 = ((lane & 7) ^ (lrow & 7)) * 8;
  const int qbase = qt * 128 + wave * 16;
  const float S2 = 0.125f * 1.44269504f;      // scale * log2(e)

  const unsigned short* kgp[2];
  const unsigned short* vgp[2];
#pragma unroll
  for (int st = 0; st < 2; st++) {
    kgp[st] = Kg + (size_t)((b * 2 + st) * 1024) * 512 + h * 64;
    vgp[st] = VTg + (size_t)(((b * 2 + st) * 8 + h) * 64) * 1024;
  }

  // Q fragments, both directions
  v8bf qf[2][2];
#pragma unroll
  for (int d = 0; d < 2; d++)
#pragma unroll
    for (int s = 0; s < 2; s++) {
      int qrow = (b * 2 + d) * 1024 + qbase + l15;
      qf[d][s] = ldfrag(&Qg[(size_t)qrow * 512 + h * 64 + s * 32 + quad * 8]);
    }

  // l-sums: add the two k-half partials, then log2
  float ll[2];
#pragma unroll
  for (int d = 0; d < 2; d++) {
    int qrow = (b * 2 + d) * 1024 + qbase + l15;
    float2 p = *(const float2*)&Lws[(size_t)qrow * 2];
    ll[d] = __log2f(p.x + p.y);
  }
  const float dll = ll[0] - ll[1];

  v4f oacc[2][4] = {};
  {
    const unsigned short* gB[4];
    unsigned short* lB[2][4];
    size_t stp[4];
#pragma unroll
    for (int t = 0; t < 4; t++) {
      int c = wave * 4 + t;                   // 16 K + 16 V chunks over 8 waves
      if (c < 16) {
        gB[t] = kgp[c >> 3] + (size_t)((c & 7) * 8 + lrow) * 512 + lc8;
        stp[t] = 32768;
        lB[0][t] = &sK[0][c >> 3][(c & 7) * 8][0];
        lB[1][t] = &sK[1][c >> 3][(c & 7) * 8][0];
      } else {
        int cv = c - 16;
        gB[t] = vgp[cv >> 3] + (size_t)((cv & 7) * 8 + lrow) * 1024 + lc8;
        stp[t] = 64;
        lB[0][t] = &sV[0][cv >> 3][(cv & 7) * 8][0];
        lB[1][t] = &sV[1][cv >> 3][(cv & 7) * 8][0];
      }
    }
#pragma unroll
    for (int t = 0; t < 4; t++) g2l(gB[t], lB[0][t]);    // tile 0

    for (int kt = 0; kt < 16; kt++) {
      drain_vmem();                           // tile kt DMA landed
      __syncthreads();                        // other buf free
      if (kt < 15) {
#pragma unroll
        for (int t = 0; t < 4; t++)
          g2l(gB[t] + (size_t)(kt + 1) * stp[t], lB[(kt + 1) & 1][t]);
      }
      const int bu = kt & 1;

      v4f acc[2][4] = {};
      __builtin_amdgcn_s_setprio(1);
#pragma unroll
      for (int s = 0; s < 2; s++)
#pragma unroll
        for (int d = 0; d < 2; d++)
#pragma unroll
          for (int j = 0; j < 4; j++) {
            v8bf kf = ldfrag(&sK[bu][1 - d][j * 16 + l15][((s * 4 + quad) ^ swl) * 8]);
            acc[d][j] = MFMA32(kf, qf[d][s], acc[d][j]);
          }
      __builtin_amdgcn_s_setprio(0);

#pragma unroll
      for (int j = 0; j < 4; j++) {
        float r0[4], r1[4];
#pragma unroll
        for (int r = 0; r < 4; r++) {
          float t = fmaf(acc[1][j][r] - acc[0][j][r], S2, dll);
          float ri = __builtin_amdgcn_rcpf(1.f + fexp2(t));
          r0[r] = ri;
          r1[r] = 1.f - ri;
        }
#if HAVE_MFMA16
        uint2 w0, w1;
        w0.x = pkbf(r0[0], r0[1]); w0.y = pkbf(r0[2], r0[3]);
        w1.x = pkbf(r1[0], r1[1]); w1.y = pkbf(r1[2], r1[3]);
        v4s af0 = __builtin_bit_cast(v4s, w0);
        v4s af1 = __builtin_bit_cast(v4s, w1);
        int vcol = ((j * 2 + (quad >> 1)) ^ swl) * 8 + (quad & 1) * 4;
        __builtin_amdgcn_s_setprio(1);
#pragma unroll
        for (int nt = 0; nt < 4; nt++) {
          v4s vf0 = ld4s(&sV[bu][1][nt * 16 + l15][vcol]);
          v4s vf1 = ld4s(&sV[bu][0][nt * 16 + l15][vcol]);
          oacc[0][nt] = MFMA16(af0, vf0, oacc[0][nt]);
          oacc[1][nt] = MFMA16(af1, vf1, oacc[1][nt]);
        }
        __builtin_amdgcn_s_setprio(0);
#else
#pragma unroll
        for (int d = 0; d < 2; d++) {
          float (&cb)[4] = (d == 0) ? r0 : r1;
          v8bf a;
#pragma unroll
          for (int jj = 0; jj < 8; jj++) {
            int src = l15 + 16 * ((jj >> 2) + (quad & 1) * 2);
            float v = __shfl(cb[jj & 3], src);
            a[jj] = __builtin_bit_cast(__bf16, f2bf(v));
          }
#pragma unroll
          for (int nt = 0; nt < 4; nt++) {
            v8bf vf = ldfrag(&sV[bu][1 - d][nt * 16 + l15]
                               [(((j & 2) * 2 + quad) ^ swl) * 8]);
            oacc[d][nt] = MFMA32(a, vf, oacc[d][nt]);
          }
        }
#endif
      }
    }
  }

#pragma unroll
  for (int d = 0; d < 2; d++)
#pragma unroll
    for (int nt = 0; nt < 4; nt++)
#pragma unroll
      for (int r = 0; r < 4; r++) {
        int row = (b * 2 + d) * 1024 + qbase + quad * 4 + r;
        int col = h * 64 + nt * 16 + l15;
        Hc[(size_t)row * 512 + col] = f2bf(oacc[d][nt][r]);
      }
}

// ---------------------------------------------------------------------------
// LayerNorm (over D=512) + gate + residual.  One WAVE per row (no LDS).
// ---------------------------------------------------------------------------
__global__ __launch_bounds__(256) void ln_kernel(
    const unsigned short* __restrict__ Pb, const float* __restrict__ hidden,
    const float* __restrict__ ln_g, const float* __restrict__ ln_b,
    const float* __restrict__ gate, float* __restrict__ out)
{
  const int row = blockIdx.x * 4 + (threadIdx.x >> 6);
  const int s = (row >> 10) & 1;
  const int lane = threadIdx.x & 63;
  const int d0 = lane * 8;

  uint4 up = *(const uint4*)&Pb[(size_t)row * 512 + d0];
  float x[8] = { lo2f(up.x), hi2f(up.x), lo2f(up.y), hi2f(up.y),
                 lo2f(up.z), hi2f(up.z), lo2f(up.w), hi2f(up.w) };
  float s1 = 0.f, s2 = 0.f;
#pragma unroll
  for (int i = 0; i < 8; i++) { s1 += x[i]; s2 += x[i] * x[i]; }
#pragma unroll
  for (int m = 1; m < 64; m <<= 1) { s1 += __shfl_xor(s1, m); s2 += __shfl_xor(s2, m); }
  float mu = s1 * (1.f / 512.f);
  float var = s2 * (1.f / 512.f) - mu * mu;
  float rs = rsqrtf(var + 1e-5f);
  float al = gate[s];

  float4 h0 = *(const float4*)&hidden[(size_t)row * 512 + d0];
  float4 h1 = *(const float4*)&hidden[(size_t)row * 512 + d0 + 4];
  float4 g0 = *(const float4*)&ln_g[s * 512 + d0];
  float4 g1 = *(const float4*)&ln_g[s * 512 + d0 + 4];
  float4 bb0 = *(const float4*)&ln_b[s * 512 + d0];
  float4 bb1 = *(const float4*)&ln_b[s * 512 + d0 + 4];
  float4 o0, o1;
  o0.x = h0.x + ((x[0] - mu) * rs * g0.x + bb0.x) * al;
  o0.y = h0.y + ((x[1] - mu) * rs * g0.y + bb0.y) * al;
  o0.z = h0.z + ((x[2] - mu) * rs * g0.z + bb0.z) * al;
  o0.w = h0.w + ((x[3] - mu) * rs * g0.w + bb0.w) * al;
  o1.x = h1.x + ((x[4] - mu) * rs * g1.x + bb1.x) * al;
  o1.y = h1.y + ((x[5] - mu) * rs * g1.y + bb1.y) * al;
  o1.z = h1.z + ((x[6] - mu) * rs * g1.z + bb1.z) * al;
  o1.w = h1.w + ((x[7] - mu) * rs * g1.w + bb1.w) * al;
  *(float4*)&out[(size_t)row * 512 + d0] = o0;
  *(float4*)&out[(size_t)row * 512 + d0 + 4] = o1;
}

// ---------------------------------------------------------------------------
extern "C" void kernel_launch(void* const* d_in, const int* in_sizes, int n_in,
                              void* d_out, int out_size, void* d_ws, size_t ws_size,
                              hipStream_t stream)
{
  const float* hidden = (const float*)d_in[0];
  const float* Wq = (const float*)d_in[1];
  const float* bq = (const float*)d_in[2];
  const float* Wk = (const float*)d_in[3];
  const float* bk = (const float*)d_in[4];
  const float* Wv = (const float*)d_in[5];
  const float* bv = (const float*)d_in[6];
  const float* Wo = (const float*)d_in[7];
  const float* bo = (const float*)d_in[8];
  const float* ln_g = (const float*)d_in[9];
  const float* ln_b = (const float*)d_in[10];
  const float* gate = (const float*)d_in[11];

  unsigned short* U = (unsigned short*)d_ws;
  unsigned short* Xbf = U;
  unsigned short* Wqb = U + 4194304;
  unsigned short* Wkb = U + 4456448;
  unsigned short* Wvb = U + 4718592;
  unsigned short* Wob = U + 4980736;
  unsigned short* Qg  = U + 5242880;
  unsigned short* Kg  = U + 9437184;
  unsigned short* VT  = U + 13631488;
  unsigned short* Hc  = U + 17825792;
  unsigned short* Pb  = (unsigned short*)((char*)d_ws + 44302336);
  float* Lws = (float*)d_ws;                  // overlays Xbf (dead after gemm1)

  convert_kernel<<<dim3(5120), 256, 0, stream>>>(hidden, Wq, Wk, Wv, Wo, Xbf);
  gemm_bt<0, 128><<<dim3(4, 64, 3), 256, 0, stream>>>(Xbf, Wqb, Wkb, Wvb, bq, bk, bv, Qg, Kg, VT);
  attn_a<<<dim3(512), 512, 0, stream>>>(Qg, Kg, Lws);
  attn_b<<<dim3(256), 512, 0, stream>>>(Qg, Kg, VT, Lws, Hc);
  gemm_bt<0, 64><<<dim3(4, 128, 1), 256, 0, stream>>>(Hc, Wob, Wob, Wob, bo, bo, bo, Pb, Pb, Pb);
  ln_kernel<<<dim3(2048), 256, 0, stream>>>(Pb, hidden, ln_g, ln_b, gate, (float*)d_out);
}

// Round 15
// 168.634 us; speedup vs baseline: 1.0125x; 1.0125x over previous
//
#include <hip/hip_runtime.h>

#define DEVI __device__ __forceinline__

typedef __bf16 v8bf __attribute__((ext_vector_type(8)));
typedef float  v4f  __attribute__((ext_vector_type(4)));
typedef short  v4s  __attribute__((ext_vector_type(4)));

DEVI unsigned short f2bf(float f) {
  unsigned u = __builtin_bit_cast(unsigned, f);
  u += 0x7fffu + ((u >> 16) & 1u);
  return (unsigned short)(u >> 16);
}
DEVI v4f MFMA32(v8bf a, v8bf b, v4f c) {
  return __builtin_amdgcn_mfma_f32_16x16x32_bf16(a, b, c, 0, 0, 0);
}
DEVI v8bf ldfrag(const unsigned short* p) {
  return __builtin_bit_cast(v8bf, *(const uint4*)p);
}
DEVI v4s ld4s(const unsigned short* p) {
  return __builtin_bit_cast(v4s, *(const uint2*)p);
}
// pack two floats -> two bf16 in one dword (round-half-up + v_perm)
DEVI unsigned pkbf(float lo, float hi) {
  unsigned a = __builtin_bit_cast(unsigned, hi) + 0x8000u;
  unsigned b = __builtin_bit_cast(unsigned, lo) + 0x8000u;
  return __builtin_amdgcn_perm(a, b, 0x07060302u);
}
DEVI float lo2f(unsigned u) { return __builtin_bit_cast(float, u << 16); }
DEVI float hi2f(unsigned u) { return __builtin_bit_cast(float, u & 0xffff0000u); }

// explicit drain of outstanding global_load_lds DMA before each barrier.
// The backend's waitcnt pass only inserts vmcnt(0) before s_barrier when it
// sees an intra-wave dependency; relying on it implicitly raced in round 4.
DEVI void drain_vmem() { asm volatile("s_waitcnt vmcnt(0)" ::: "memory"); }

#if __has_builtin(__builtin_amdgcn_exp2f)
DEVI float fexp2(float x) { return __builtin_amdgcn_exp2f(x); }
#else
DEVI float fexp2(float x) { return exp2f(x); }
#endif

#if __has_builtin(__builtin_amdgcn_mfma_f32_16x16x16bf16_1k)
#define HAVE_MFMA16 1
DEVI v4f MFMA16(v4s a, v4s b, v4f c) {
  return __builtin_amdgcn_mfma_f32_16x16x16bf16_1k(a, b, c, 0, 0, 0);
}
#else
#define HAVE_MFMA16 0
#endif

// async global->LDS, 16B per lane; per-lane global addresses pre-apply the
// XOR swizzle (LDS side must stay contiguous).
#if __has_builtin(__builtin_amdgcn_global_load_lds)
DEVI void g2l(const unsigned short* g, unsigned short* l) {
  __builtin_amdgcn_global_load_lds(
      (const __attribute__((address_space(1))) unsigned int*)g,
      (__attribute__((address_space(3))) unsigned int*)l, 16, 0, 0);
}
#else
DEVI void g2l(const unsigned short* g, unsigned short* l) {
  *(uint4*)((char*)l + (threadIdx.x & 63) * 16) = *(const uint4*)g;
}
#endif

// ---------------------------------------------------------------------------
// fp32 -> bf16 conversion of X (4,2,1024,512) and Wq/Wk/Wv/Wo (512x512 each).
// ---------------------------------------------------------------------------
__global__ __launch_bounds__(256) void convert_kernel(
    const float* __restrict__ X, const float* __restrict__ Wq,
    const float* __restrict__ Wk, const float* __restrict__ Wv,
    const float* __restrict__ Wo, unsigned short* __restrict__ dst)
{
  int t = blockIdx.x * 256 + threadIdx.x;
  int idx = t * 4;
  const float* src;
  if (idx < 4194304) {
    src = X + idx;
  } else {
    int u = idx - 4194304;
    int w = u >> 18;
    const float* W = (w == 0) ? Wq : (w == 1) ? Wk : (w == 2) ? Wv : Wo;
    src = W + (u & 262143);
  }
  float4 f = *(const float4*)src;
  uint2 o;
  o.x = pkbf(f.x, f.y);
  o.y = pkbf(f.z, f.w);
  *(uint2*)&dst[idx] = o;
}

// ---------------------------------------------------------------------------
// C[m][n] = sum_k A[m][k]*W[n][k] + bias[n]   (BT GEMM, M=8192 N=512 K=512)
// BMx128 tile, 4 waves, global_load_lds staging, XOR-swizzled LDS.
// DOUBLE-BUFFERED: one barrier per k-step; tile kt+1 is issued right after
// the barrier and has the whole compute(kt) phase in flight.  An EXPLICIT
// s_waitcnt vmcnt(0) before each barrier enforces the DMA->barrier->ds_read
// protocol (the backend omits it after full unroll -> round-4 race).
// XCD-chunked swizzle (T1), nwg%8==0 for both grids.
// OUTM=0 bf16 out.  z==2 (V transposed into VT) routes the output tile
// through LDS so VT global stores are 4 full rows x 256 B per instruction.
// OUTM=1 fp32 out.
// ---------------------------------------------------------------------------
template<int OUTM, int BM>
__global__ __launch_bounds__(256) void gemm_bt(
    const unsigned short* __restrict__ A,
    const unsigned short* __restrict__ W0, const unsigned short* __restrict__ W1,
    const unsigned short* __restrict__ W2,
    const float* __restrict__ b0, const float* __restrict__ b1, const float* __restrict__ b2,
    void* __restrict__ C0, void* __restrict__ C1, void* __restrict__ C2)
{
  const int K = 512, N = 512;
  const int MI = BM / 32;
  const int PER = (BM / 8 + 16) / 4;          // g2l chunks per wave
  __shared__ unsigned short sAB[2][(BM + 128) * 64];

  // XCD-chunked blockIdx swizzle (bijective; nwg = 768 or 512, both %8==0)
  const int gx = gridDim.x, gy = gridDim.y;
  const int nwg = gx * gy * gridDim.z;
  const int lin = (blockIdx.z * gy + blockIdx.y) * gx + blockIdx.x;
  const int wsw = (lin & 7) * (nwg >> 3) + (lin >> 3);
  const int bx = wsw % gx, by = (wsw / gx) % gy;
  const int z = wsw / (gx * gy);

  const unsigned short* W = (z == 0) ? W0 : (z == 1) ? W1 : W2;
  const float* bias = (z == 0) ? b0 : (z == 1) ? b1 : b2;
  void* C = (z == 0) ? C0 : (z == 1) ? C1 : C2;

  const int tid = threadIdx.x;
  const int lane = tid & 63, wave = tid >> 6;
  const int l15 = lane & 15, quad = lane >> 4, swl = l15 & 7;
  const int lrow = lane >> 3;
  const int lc8 = ((lane & 7) ^ (lrow & 7)) * 8;
  const int wm = (wave >> 1) * (BM / 2), wn = (wave & 1) * 64;
  const int mbase = by * BM, nbase = bx * 128;

  const unsigned short* gsrc[PER];
  int loff[PER];
#pragma unroll
  for (int t = 0; t < PER; t++) {
    int c = wave * PER + t;
    loff[t] = c * 512;
    if (c < BM / 8) gsrc[t] = A + (size_t)(mbase + c * 8 + lrow) * K + lc8;
    else            gsrc[t] = W + (size_t)(nbase + (c - BM / 8) * 8 + lrow) * K + lc8;
  }

  v4f acc[MI][4] = {};

#pragma unroll
  for (int t = 0; t < PER; t++) g2l(gsrc[t], &sAB[0][loff[t]]);   // tile 0

  for (int kt = 0; kt < K / 64; kt++) {
    drain_vmem();                             // tile kt DMA landed (explicit!)
    __syncthreads();                          // all waves' tile kt visible
    if (kt < K / 64 - 1) {
#pragma unroll
      for (int t = 0; t < PER; t++)
        g2l(gsrc[t] + (kt + 1) * 64, &sAB[(kt + 1) & 1][loff[t]]);
    }
    const int bu = kt & 1;
#pragma unroll
    for (int s = 0; s < 2; s++) {
      v8bf af[MI], bf[4];
#pragma unroll
      for (int i = 0; i < MI; i++)
        af[i] = ldfrag(&sAB[bu][(wm + i * 16 + l15) * 64 + ((s * 4 + quad) ^ swl) * 8]);
#pragma unroll
      for (int j = 0; j < 4; j++)
        bf[j] = ldfrag(&sAB[bu][(BM + wn + j * 16 + l15) * 64 + ((s * 4 + quad) ^ swl) * 8]);
#pragma unroll
      for (int i = 0; i < MI; i++)
#pragma unroll
        for (int j = 0; j < 4; j++)
          acc[i][j] = MFMA32(af[i], bf[j], acc[i][j]);
    }
  }

  if (OUTM == 0 && BM == 128 && z == 2) {
    // ---- VT epilogue via LDS transpose (coalesced 256 B row segments) ----
    const int TP = 136;                       // padded t'-pitch (16B-aligned)
    unsigned short* T = &sAB[0][0];           // 128*136*2 B = 34 KB, sAB dead
    __syncthreads();                          // all K-loop LDS reads done
#pragma unroll
    for (int i = 0; i < MI; i++)
#pragma unroll
      for (int j = 0; j < 4; j++) {
        int tp = wm + i * 16 + quad * 4;      // t' = row0 - mbase
        int c  = wn + j * 16 + l15;           // hd-col index = col - nbase
        int col = nbase + c;
        float v[4];
#pragma unroll
        for (int r = 0; r < 4; r++) v[r] = acc[i][j][r] + bias[col];
        uint2 o;
        o.x = pkbf(v[0], v[1]);
        o.y = pkbf(v[2], v[3]);
        *(uint2*)&T[c * TP + tp] = o;
      }
    __syncthreads();                          // tile staged
    const int bs = mbase >> 10, tbase = mbase & 1023;
    const int hh0 = nbase >> 6;
#pragma unroll
    for (int it = 0; it < 8; it++) {
      int rh = wave * 32 + it * 4 + quad;     // c-index = VT row within tile
      uint4 d = *(const uint4*)&T[rh * TP + l15 * 8];
      int rowIdx = (bs * 8 + hh0 + (rh >> 6)) * 64 + (rh & 63);
      *(uint4*)&((unsigned short*)C)[(size_t)rowIdx * 1024 + tbase + l15 * 8] = d;
    }
  } else {
#pragma unroll
    for (int i = 0; i < MI; i++)
#pragma unroll
      for (int j = 0; j < 4; j++) {
        int row0 = mbase + wm + i * 16 + quad * 4;
        int col = nbase + wn + j * 16 + l15;
        float v[4];
#pragma unroll
        for (int r = 0; r < 4; r++) v[r] = acc[i][j][r] + bias[col];
        if (OUTM == 1) {
#pragma unroll
          for (int r = 0; r < 4; r++) ((float*)C)[(size_t)(row0 + r) * N + col] = v[r];
        } else if (z == 2) {
          int bs = row0 >> 10, t0 = row0 & 1023;
          int hh = col >> 6, hd = col & 63;
          uint2 o;
          o.x = pkbf(v[0], v[1]);
          o.y = pkbf(v[2], v[3]);
          *(uint2*)&((unsigned short*)C)[(size_t)((bs * 8 + hh) * 64 + hd) * 1024 + t0] = o;
        } else {
#pragma unroll
          for (int r = 0; r < 4; r++)
            ((unsigned short*)C)[(size_t)(row0 + r) * N + col] = f2bf(v[r]);
        }
      }
  }
}

// ---------------------------------------------------------------------------
// attn pass A (standalone, k-split 2x): l-sums only.  ROUND-13 FORM (4-wave,
// grid 1024, 4 blocks/CU): the round-14 qt-merge regressed because halving
// the independent blocks/CU (4 -> 2) cost more desync overlap than the
// staging dedup saved.  Grid 1024: bid&31 = (b,h) pair, (bid>>5)&15 = qt,
// bid>>9 = k-half.  LDS = sK only (32 KB).  s_setprio around MFMA (T5).
// ---------------------------------------------------------------------------
__global__ __launch_bounds__(256, 4) void attn_a(
    const unsigned short* __restrict__ Qg, const unsigned short* __restrict__ Kg,
    float* __restrict__ Lws)
{
  __shared__ unsigned short sK[2][2][64][64];   // [buf][stream]

  const int pair = blockIdx.x & 31;           // h = pair&7 -> XCD L2 affinity
  const int b = pair >> 3, h = pair & 7;
  const int qt = (blockIdx.x >> 5) & 15;
  const int kh = blockIdx.x >> 9;             // k-half 0/1
  const int tid = threadIdx.x;
  const int lane = tid & 63, wave = tid >> 6;
  const int l15 = lane & 15, quad = lane >> 4, swl = l15 & 7;
  const int lrow = lane >> 3;
  const int lc8 = ((lane & 7) ^ (lrow & 7)) * 8;
  const int qbase = qt * 64 + wave * 16;
  const float S2 = 0.125f * 1.44269504f;      // scale * log2(e)

  const unsigned short* kgp[2];
#pragma unroll
  for (int st = 0; st < 2; st++)
    kgp[st] = Kg + (size_t)((b * 2 + st) * 1024) * 512 + h * 64;

  // Q fragments, both directions
  v8bf qf[2][2];
#pragma unroll
  for (int d = 0; d < 2; d++)
#pragma unroll
    for (int s = 0; s < 2; s++) {
      int qrow = (b * 2 + d) * 1024 + qbase + l15;
      qf[d][s] = ldfrag(&Qg[(size_t)qrow * 512 + h * 64 + s * 32 + quad * 8]);
    }

  const unsigned short* gA[4];
  unsigned short* lA[2][4];
#pragma unroll
  for (int t = 0; t < 4; t++) {
    int c = wave * 4 + t;                     // 16 K chunks over 4 waves
    gA[t] = kgp[c >> 3] + (size_t)((c & 7) * 8 + lrow) * 512 + lc8
            + (size_t)kh * 262144;            // k-half base (8 tiles)
    lA[0][t] = &sK[0][c >> 3][(c & 7) * 8][0];
    lA[1][t] = &sK[1][c >> 3][(c & 7) * 8][0];
  }

  float lacc[2] = {0.f, 0.f};
#pragma unroll
  for (int t = 0; t < 4; t++) g2l(gA[t], lA[0][t]);      // tile 0

  for (int kt = 0; kt < 8; kt++) {
    drain_vmem();                             // tile kt DMA landed
    __syncthreads();
    if (kt < 7) {
#pragma unroll
      for (int t = 0; t < 4; t++)
        g2l(gA[t] + (size_t)(kt + 1) * 32768, lA[(kt + 1) & 1][t]);
    }
    const int bu = kt & 1;
    v4f acc[2][4] = {};
    __builtin_amdgcn_s_setprio(1);
#pragma unroll
    for (int s = 0; s < 2; s++)
#pragma unroll
      for (int d = 0; d < 2; d++)
#pragma unroll
        for (int j = 0; j < 4; j++) {
          v8bf kf = ldfrag(&sK[bu][1 - d][j * 16 + l15][((s * 4 + quad) ^ swl) * 8]);
          acc[d][j] = MFMA32(kf, qf[d][s], acc[d][j]);
        }
    __builtin_amdgcn_s_setprio(0);
#pragma unroll
    for (int d = 0; d < 2; d++)
#pragma unroll
      for (int j = 0; j < 4; j++)
#pragma unroll
        for (int r = 0; r < 4; r++)
          lacc[d] += fexp2(acc[d][j][r] * S2);
  }

  float lv[2];
#pragma unroll
  for (int d = 0; d < 2; d++) {
    float v = lacc[d];
    v += __shfl_xor(v, 16);
    v += __shfl_xor(v, 32);
    lv[d] = v;                                // partial row-sum (linear domain)
  }
  if (quad == 0) {
#pragma unroll
    for (int d = 0; d < 2; d++) {
      int qrow = (b * 2 + d) * 1024 + qbase + l15;
      Lws[(size_t)qrow * 2 + kh] = lv[d];
    }
  }
}

// ---------------------------------------------------------------------------
// attn pass B: combine + PV.  8-WAVE QT-MERGE (round 13, verified): 512
// threads, block owns 128 q-rows, grid 256 = 1 block/CU; one staged K/V tile
// serves 8 waves.  Sync skeleton: drain -> barrier -> issue g2l(kt+1) ->
// compute(kt).  Staging: 32 chunks over 8 waves = 4/wave.  s_setprio (T5).
// ---------------------------------------------------------------------------
__global__ __launch_bounds__(512, 2) void attn_b(
    const unsigned short* __restrict__ Qg, const unsigned short* __restrict__ Kg,
    const unsigned short* __restrict__ VTg, const float* __restrict__ Lws,
    unsigned short* __restrict__ Hc)
{
  __shared__ unsigned short sK[2][2][64][64];   // [buf][stream]
  __shared__ unsigned short sV[2][2][64][64];

  const int pair = blockIdx.x & 31;           // h = pair&7 -> XCD L2 affinity
  const int b = pair >> 3, h = pair & 7;
  const int qt = blockIdx.x >> 5;             // 0..7 (128 q-rows per block)
  const int tid = threadIdx.x;
  const int lane = tid & 63, wave = tid >> 6; // 0..7
  const int l15 = lane & 15, quad = lane >> 4, swl = l15 & 7;
  const int lrow = lane >> 3;
  const int lc8 = ((lane & 7) ^ (lrow & 7)) * 8;
  const int qbase = qt * 128 + wave * 16;
  const float S2 = 0.125f * 1.44269504f;      // scale * log2(e)

  const unsigned short* kgp[2];
  const unsigned short* vgp[2];
#pragma unroll
  for (int st = 0; st < 2; st++) {
    kgp[st] = Kg + (size_t)((b * 2 + st) * 1024) * 512 + h * 64;
    vgp[st] = VTg + (size_t)(((b * 2 + st) * 8 + h) * 64) * 1024;
  }

  // Q fragments, both directions
  v8bf qf[2][2];
#pragma unroll
  for (int d = 0; d < 2; d++)
#pragma unroll
    for (int s = 0; s < 2; s++) {
      int qrow = (b * 2 + d) * 1024 + qbase + l15;
      qf[d][s] = ldfrag(&Qg[(size_t)qrow * 512 + h * 64 + s * 32 + quad * 8]);
    }

  // l-sums: add the two k-half partials, then log2
  float ll[2];
#pragma unroll
  for (int d = 0; d < 2; d++) {
    int qrow = (b * 2 + d) * 1024 + qbase + l15;
    float2 p = *(const float2*)&Lws[(size_t)qrow * 2];
    ll[d] = __log2f(p.x + p.y);
  }
  const float dll = ll[0] - ll[1];

  v4f oacc[2][4] = {};
  {
    const unsigned short* gB[4];
    unsigned short* lB[2][4];
    size_t stp[4];
#pragma unroll
    for (int t = 0; t < 4; t++) {
      int c = wave * 4 + t;                   // 16 K + 16 V chunks over 8 waves
      if (c < 16) {
        gB[t] = kgp[c >> 3] + (size_t)((c & 7) * 8 + lrow) * 512 + lc8;
        stp[t] = 32768;
        lB[0][t] = &sK[0][c >> 3][(c & 7) * 8][0];
        lB[1][t] = &sK[1][c >> 3][(c & 7) * 8][0];
      } else {
        int cv = c - 16;
        gB[t] = vgp[cv >> 3] + (size_t)((cv & 7) * 8 + lrow) * 1024 + lc8;
        stp[t] = 64;
        lB[0][t] = &sV[0][cv >> 3][(cv & 7) * 8][0];
        lB[1][t] = &sV[1][cv >> 3][(cv & 7) * 8][0];
      }
    }
#pragma unroll
    for (int t = 0; t < 4; t++) g2l(gB[t], lB[0][t]);    // tile 0

    for (int kt = 0; kt < 16; kt++) {
      drain_vmem();                           // tile kt DMA landed
      __syncthreads();                        // other buf free
      if (kt < 15) {
#pragma unroll
        for (int t = 0; t < 4; t++)
          g2l(gB[t] + (size_t)(kt + 1) * stp[t], lB[(kt + 1) & 1][t]);
      }
      const int bu = kt & 1;

      v4f acc[2][4] = {};
      __builtin_amdgcn_s_setprio(1);
#pragma unroll
      for (int s = 0; s < 2; s++)
#pragma unroll
        for (int d = 0; d < 2; d++)
#pragma unroll
          for (int j = 0; j < 4; j++) {
            v8bf kf = ldfrag(&sK[bu][1 - d][j * 16 + l15][((s * 4 + quad) ^ swl) * 8]);
            acc[d][j] = MFMA32(kf, qf[d][s], acc[d][j]);
          }
      __builtin_amdgcn_s_setprio(0);

#pragma unroll
      for (int j = 0; j < 4; j++) {
        float r0[4], r1[4];
#pragma unroll
        for (int r = 0; r < 4; r++) {
          float t = fmaf(acc[1][j][r] - acc[0][j][r], S2, dll);
          float ri = __builtin_amdgcn_rcpf(1.f + fexp2(t));
          r0[r] = ri;
          r1[r] = 1.f - ri;
        }
#if HAVE_MFMA16
        uint2 w0, w1;
        w0.x = pkbf(r0[0], r0[1]); w0.y = pkbf(r0[2], r0[3]);
        w1.x = pkbf(r1[0], r1[1]); w1.y = pkbf(r1[2], r1[3]);
        v4s af0 = __builtin_bit_cast(v4s, w0);
        v4s af1 = __builtin_bit_cast(v4s, w1);
        int vcol = ((j * 2 + (quad >> 1)) ^ swl) * 8 + (quad & 1) * 4;
        __builtin_amdgcn_s_setprio(1);
#pragma unroll
        for (int nt = 0; nt < 4; nt++) {
          v4s vf0 = ld4s(&sV[bu][1][nt * 16 + l15][vcol]);
          v4s vf1 = ld4s(&sV[bu][0][nt * 16 + l15][vcol]);
          oacc[0][nt] = MFMA16(af0, vf0, oacc[0][nt]);
          oacc[1][nt] = MFMA16(af1, vf1, oacc[1][nt]);
        }
        __builtin_amdgcn_s_setprio(0);
#else
#pragma unroll
        for (int d = 0; d < 2; d++) {
          float (&cb)[4] = (d == 0) ? r0 : r1;
          v8bf a;
#pragma unroll
          for (int jj = 0; jj < 8; jj++) {
            int src = l15 + 16 * ((jj >> 2) + (quad & 1) * 2);
            float v = __shfl(cb[jj & 3], src);
            a[jj] = __builtin_bit_cast(__bf16, f2bf(v));
          }
#pragma unroll
          for (int nt = 0; nt < 4; nt++) {
            v8bf vf = ldfrag(&sV[bu][1 - d][nt * 16 + l15]
                               [(((j & 2) * 2 + quad) ^ swl) * 8]);
            oacc[d][nt] = MFMA32(a, vf, oacc[d][nt]);
          }
        }
#endif
      }
    }
  }

#pragma unroll
  for (int d = 0; d < 2; d++)
#pragma unroll
    for (int nt = 0; nt < 4; nt++)
#pragma unroll
      for (int r = 0; r < 4; r++) {
        int row = (b * 2 + d) * 1024 + qbase + quad * 4 + r;
        int col = h * 64 + nt * 16 + l15;
        Hc[(size_t)row * 512 + col] = f2bf(oacc[d][nt][r]);
      }
}

// ---------------------------------------------------------------------------
// LayerNorm (over D=512) + gate + residual.  One WAVE per row (no LDS).
// ---------------------------------------------------------------------------
__global__ __launch_bounds__(256) void ln_kernel(
    const unsigned short* __restrict__ Pb, const float* __restrict__ hidden,
    const float* __restrict__ ln_g, const float* __restrict__ ln_b,
    const float* __restrict__ gate, float* __restrict__ out)
{
  const int row = blockIdx.x * 4 + (threadIdx.x >> 6);
  const int s = (row >> 10) & 1;
  const int lane = threadIdx.x & 63;
  const int d0 = lane * 8;

  uint4 up = *(const uint4*)&Pb[(size_t)row * 512 + d0];
  float x[8] = { lo2f(up.x), hi2f(up.x), lo2f(up.y), hi2f(up.y),
                 lo2f(up.z), hi2f(up.z), lo2f(up.w), hi2f(up.w) };
  float s1 = 0.f, s2 = 0.f;
#pragma unroll
  for (int i = 0; i < 8; i++) { s1 += x[i]; s2 += x[i] * x[i]; }
#pragma unroll
  for (int m = 1; m < 64; m <<= 1) { s1 += __shfl_xor(s1, m); s2 += __shfl_xor(s2, m); }
  float mu = s1 * (1.f / 512.f);
  float var = s2 * (1.f / 512.f) - mu * mu;
  float rs = rsqrtf(var + 1e-5f);
  float al = gate[s];

  float4 h0 = *(const float4*)&hidden[(size_t)row * 512 + d0];
  float4 h1 = *(const float4*)&hidden[(size_t)row * 512 + d0 + 4];
  float4 g0 = *(const float4*)&ln_g[s * 512 + d0];
  float4 g1 = *(const float4*)&ln_g[s * 512 + d0 + 4];
  float4 bb0 = *(const float4*)&ln_b[s * 512 + d0];
  float4 bb1 = *(const float4*)&ln_b[s * 512 + d0 + 4];
  float4 o0, o1;
  o0.x = h0.x + ((x[0] - mu) * rs * g0.x + bb0.x) * al;
  o0.y = h0.y + ((x[1] - mu) * rs * g0.y + bb0.y) * al;
  o0.z = h0.z + ((x[2] - mu) * rs * g0.z + bb0.z) * al;
  o0.w = h0.w + ((x[3] - mu) * rs * g0.w + bb0.w) * al;
  o1.x = h1.x + ((x[4] - mu) * rs * g1.x + bb1.x) * al;
  o1.y = h1.y + ((x[5] - mu) * rs * g1.y + bb1.y) * al;
  o1.z = h1.z + ((x[6] - mu) * rs * g1.z + bb1.z) * al;
  o1.w = h1.w + ((x[7] - mu) * rs * g1.w + bb1.w) * al;
  *(float4*)&out[(size_t)row * 512 + d0] = o0;
  *(float4*)&out[(size_t)row * 512 + d0 + 4] = o1;
}

// ---------------------------------------------------------------------------
extern "C" void kernel_launch(void* const* d_in, const int* in_sizes, int n_in,
                              void* d_out, int out_size, void* d_ws, size_t ws_size,
                              hipStream_t stream)
{
  const float* hidden = (const float*)d_in[0];
  const float* Wq = (const float*)d_in[1];
  const float* bq = (const float*)d_in[2];
  const float* Wk = (const float*)d_in[3];
  const float* bk = (const float*)d_in[4];
  const float* Wv = (const float*)d_in[5];
  const float* bv = (const float*)d_in[6];
  const float* Wo = (const float*)d_in[7];
  const float* bo = (const float*)d_in[8];
  const float* ln_g = (const float*)d_in[9];
  const float* ln_b = (const float*)d_in[10];
  const float* gate = (const float*)d_in[11];

  unsigned short* U = (unsigned short*)d_ws;
  unsigned short* Xbf = U;
  unsigned short* Wqb = U + 4194304;
  unsigned short* Wkb = U + 4456448;
  unsigned short* Wvb = U + 4718592;
  unsigned short* Wob = U + 4980736;
  unsigned short* Qg  = U + 5242880;
  unsigned short* Kg  = U + 9437184;
  unsigned short* VT  = U + 13631488;
  unsigned short* Hc  = U + 17825792;
  unsigned short* Pb  = (unsigned short*)((char*)d_ws + 44302336);
  float* Lws = (float*)d_ws;                  // overlays Xbf (dead after gemm1)

  convert_kernel<<<dim3(5120), 256, 0, stream>>>(hidden, Wq, Wk, Wv, Wo, Xbf);
  gemm_bt<0, 128><<<dim3(4, 64, 3), 256, 0, stream>>>(Xbf, Wqb, Wkb, Wvb, bq, bk, bv, Qg, Kg, VT);
  attn_a<<<dim3(1024), 256, 0, stream>>>(Qg, Kg, Lws);
  attn_b<<<dim3(256), 512, 0, stream>>>(Qg, Kg, VT, Lws, Hc);
  gemm_bt<0, 64><<<dim3(4, 128, 1), 256, 0, stream>>>(Hc, Wob, Wob, Wob, bo, bo, bo, Pb, Pb, Pb);
  ln_kernel<<<dim3(2048), 256, 0, stream>>>(Pb, hidden, ln_g, ln_b, gate, (float*)d_out);
}

// Round 16
// 168.474 us; speedup vs baseline: 1.0135x; 1.0009x over previous
//
#include <hip/hip_runtime.h>

#define DEVI __device__ __forceinline__

typedef __bf16 v8bf __attribute__((ext_vector_type(8)));
typedef float  v4f  __attribute__((ext_vector_type(4)));
typedef short  v4s  __attribute__((ext_vector_type(4)));

DEVI unsigned short f2bf(float f) {
  unsigned u = __builtin_bit_cast(unsigned, f);
  u += 0x7fffu + ((u >> 16) & 1u);
  return (unsigned short)(u >> 16);
}
DEVI v4f MFMA32(v8bf a, v8bf b, v4f c) {
  return __builtin_amdgcn_mfma_f32_16x16x32_bf16(a, b, c, 0, 0, 0);
}
DEVI v8bf ldfrag(const unsigned short* p) {
  return __builtin_bit_cast(v8bf, *(const uint4*)p);
}
DEVI v4s ld4s(const unsigned short* p) {
  return __builtin_bit_cast(v4s, *(const uint2*)p);
}
// pack two floats -> two bf16 in one dword (round-half-up + v_perm)
DEVI unsigned pkbf(float lo, float hi) {
  unsigned a = __builtin_bit_cast(unsigned, hi) + 0x8000u;
  unsigned b = __builtin_bit_cast(unsigned, lo) + 0x8000u;
  return __builtin_amdgcn_perm(a, b, 0x07060302u);
}
DEVI float lo2f(unsigned u) { return __builtin_bit_cast(float, u << 16); }
DEVI float hi2f(unsigned u) { return __builtin_bit_cast(float, u & 0xffff0000u); }

// explicit drain of outstanding global_load_lds DMA before each barrier.
// The backend's waitcnt pass only inserts vmcnt(0) before s_barrier when it
// sees an intra-wave dependency; relying on it implicitly raced in round 4.
DEVI void drain_vmem() { asm volatile("s_waitcnt vmcnt(0)" ::: "memory"); }

#if __has_builtin(__builtin_amdgcn_exp2f)
DEVI float fexp2(float x) { return __builtin_amdgcn_exp2f(x); }
#else
DEVI float fexp2(float x) { return exp2f(x); }
#endif

#if __has_builtin(__builtin_amdgcn_mfma_f32_16x16x16bf16_1k)
#define HAVE_MFMA16 1
DEVI v4f MFMA16(v4s a, v4s b, v4f c) {
  return __builtin_amdgcn_mfma_f32_16x16x16bf16_1k(a, b, c, 0, 0, 0);
}
#else
#define HAVE_MFMA16 0
#endif

// async global->LDS, 16B per lane; per-lane global addresses pre-apply the
// XOR swizzle (LDS side must stay contiguous).
#if __has_builtin(__builtin_amdgcn_global_load_lds)
DEVI void g2l(const unsigned short* g, unsigned short* l) {
  __builtin_amdgcn_global_load_lds(
      (const __attribute__((address_space(1))) unsigned int*)g,
      (__attribute__((address_space(3))) unsigned int*)l, 16, 0, 0);
}
#else
DEVI void g2l(const unsigned short* g, unsigned short* l) {
  *(uint4*)((char*)l + (threadIdx.x & 63) * 16) = *(const uint4*)g;
}
#endif

// ---------------------------------------------------------------------------
// fp32 -> bf16 conversion of X (4,2,1024,512) and Wq/Wk/Wv/Wo (512x512 each).
// ---------------------------------------------------------------------------
__global__ __launch_bounds__(256) void convert_kernel(
    const float* __restrict__ X, const float* __restrict__ Wq,
    const float* __restrict__ Wk, const float* __restrict__ Wv,
    const float* __restrict__ Wo, unsigned short* __restrict__ dst)
{
  int t = blockIdx.x * 256 + threadIdx.x;
  int idx = t * 4;
  const float* src;
  if (idx < 4194304) {
    src = X + idx;
  } else {
    int u = idx - 4194304;
    int w = u >> 18;
    const float* W = (w == 0) ? Wq : (w == 1) ? Wk : (w == 2) ? Wv : Wo;
    src = W + (u & 262143);
  }
  float4 f = *(const float4*)src;
  uint2 o;
  o.x = pkbf(f.x, f.y);
  o.y = pkbf(f.z, f.w);
  *(uint2*)&dst[idx] = o;
}

// ---------------------------------------------------------------------------
// C[m][n] = sum_k A[m][k]*W[n][k] + bias[n]   (BT GEMM, M=8192 N=512 K=512)
// BMx128 tile, 4 waves, global_load_lds staging, XOR-swizzled LDS.
// DOUBLE-BUFFERED: one barrier per k-step; tile kt+1 is issued right after
// the barrier and has the whole compute(kt) phase in flight.  An EXPLICIT
// s_waitcnt vmcnt(0) before each barrier enforces the DMA->barrier->ds_read
// protocol (the backend omits it after full unroll -> round-4 race).
// XCD-chunked swizzle (T1), nwg%8==0 for both grids.
// OUTM=0 bf16 out.  z==2 (V transposed into VT) routes the output tile
// through LDS so VT global stores are 4 full rows x 256 B per instruction.
// OUTM=1 fp32 out.
// ---------------------------------------------------------------------------
template<int OUTM, int BM>
__global__ __launch_bounds__(256) void gemm_bt(
    const unsigned short* __restrict__ A,
    const unsigned short* __restrict__ W0, const unsigned short* __restrict__ W1,
    const unsigned short* __restrict__ W2,
    const float* __restrict__ b0, const float* __restrict__ b1, const float* __restrict__ b2,
    void* __restrict__ C0, void* __restrict__ C1, void* __restrict__ C2)
{
  const int K = 512, N = 512;
  const int MI = BM / 32;
  const int PER = (BM / 8 + 16) / 4;          // g2l chunks per wave
  __shared__ unsigned short sAB[2][(BM + 128) * 64];

  // XCD-chunked blockIdx swizzle (bijective; nwg = 768 or 512, both %8==0)
  const int gx = gridDim.x, gy = gridDim.y;
  const int nwg = gx * gy * gridDim.z;
  const int lin = (blockIdx.z * gy + blockIdx.y) * gx + blockIdx.x;
  const int wsw = (lin & 7) * (nwg >> 3) + (lin >> 3);
  const int bx = wsw % gx, by = (wsw / gx) % gy;
  const int z = wsw / (gx * gy);

  const unsigned short* W = (z == 0) ? W0 : (z == 1) ? W1 : W2;
  const float* bias = (z == 0) ? b0 : (z == 1) ? b1 : b2;
  void* C = (z == 0) ? C0 : (z == 1) ? C1 : C2;

  const int tid = threadIdx.x;
  const int lane = tid & 63, wave = tid >> 6;
  const int l15 = lane & 15, quad = lane >> 4, swl = l15 & 7;
  const int lrow = lane >> 3;
  const int lc8 = ((lane & 7) ^ (lrow & 7)) * 8;
  const int wm = (wave >> 1) * (BM / 2), wn = (wave & 1) * 64;
  const int mbase = by * BM, nbase = bx * 128;

  const unsigned short* gsrc[PER];
  int loff[PER];
#pragma unroll
  for (int t = 0; t < PER; t++) {
    int c = wave * PER + t;
    loff[t] = c * 512;
    if (c < BM / 8) gsrc[t] = A + (size_t)(mbase + c * 8 + lrow) * K + lc8;
    else            gsrc[t] = W + (size_t)(nbase + (c - BM / 8) * 8 + lrow) * K + lc8;
  }

  v4f acc[MI][4] = {};

#pragma unroll
  for (int t = 0; t < PER; t++) g2l(gsrc[t], &sAB[0][loff[t]]);   // tile 0

  for (int kt = 0; kt < K / 64; kt++) {
    drain_vmem();                             // tile kt DMA landed (explicit!)
    __syncthreads();                          // all waves' tile kt visible
    if (kt < K / 64 - 1) {
#pragma unroll
      for (int t = 0; t < PER; t++)
        g2l(gsrc[t] + (kt + 1) * 64, &sAB[(kt + 1) & 1][loff[t]]);
    }
    const int bu = kt & 1;
#pragma unroll
    for (int s = 0; s < 2; s++) {
      v8bf af[MI], bf[4];
#pragma unroll
      for (int i = 0; i < MI; i++)
        af[i] = ldfrag(&sAB[bu][(wm + i * 16 + l15) * 64 + ((s * 4 + quad) ^ swl) * 8]);
#pragma unroll
      for (int j = 0; j < 4; j++)
        bf[j] = ldfrag(&sAB[bu][(BM + wn + j * 16 + l15) * 64 + ((s * 4 + quad) ^ swl) * 8]);
#pragma unroll
      for (int i = 0; i < MI; i++)
#pragma unroll
        for (int j = 0; j < 4; j++)
          acc[i][j] = MFMA32(af[i], bf[j], acc[i][j]);
    }
  }

  if (OUTM == 0 && BM == 128 && z == 2) {
    // ---- VT epilogue via LDS transpose (coalesced 256 B row segments) ----
    const int TP = 136;                       // padded t'-pitch (16B-aligned)
    unsigned short* T = &sAB[0][0];           // 128*136*2 B = 34 KB, sAB dead
    __syncthreads();                          // all K-loop LDS reads done
#pragma unroll
    for (int i = 0; i < MI; i++)
#pragma unroll
      for (int j = 0; j < 4; j++) {
        int tp = wm + i * 16 + quad * 4;      // t' = row0 - mbase
        int c  = wn + j * 16 + l15;           // hd-col index = col - nbase
        int col = nbase + c;
        float v[4];
#pragma unroll
        for (int r = 0; r < 4; r++) v[r] = acc[i][j][r] + bias[col];
        uint2 o;
        o.x = pkbf(v[0], v[1]);
        o.y = pkbf(v[2], v[3]);
        *(uint2*)&T[c * TP + tp] = o;
      }
    __syncthreads();                          // tile staged
    const int bs = mbase >> 10, tbase = mbase & 1023;
    const int hh0 = nbase >> 6;
#pragma unroll
    for (int it = 0; it < 8; it++) {
      int rh = wave * 32 + it * 4 + quad;     // c-index = VT row within tile
      uint4 d = *(const uint4*)&T[rh * TP + l15 * 8];
      int rowIdx = (bs * 8 + hh0 + (rh >> 6)) * 64 + (rh & 63);
      *(uint4*)&((unsigned short*)C)[(size_t)rowIdx * 1024 + tbase + l15 * 8] = d;
    }
  } else {
#pragma unroll
    for (int i = 0; i < MI; i++)
#pragma unroll
      for (int j = 0; j < 4; j++) {
        int row0 = mbase + wm + i * 16 + quad * 4;
        int col = nbase + wn + j * 16 + l15;
        float v[4];
#pragma unroll
        for (int r = 0; r < 4; r++) v[r] = acc[i][j][r] + bias[col];
        if (OUTM == 1) {
#pragma unroll
          for (int r = 0; r < 4; r++) ((float*)C)[(size_t)(row0 + r) * N + col] = v[r];
        } else if (z == 2) {
          int bs = row0 >> 10, t0 = row0 & 1023;
          int hh = col >> 6, hd = col & 63;
          uint2 o;
          o.x = pkbf(v[0], v[1]);
          o.y = pkbf(v[2], v[3]);
          *(uint2*)&((unsigned short*)C)[(size_t)((bs * 8 + hh) * 64 + hd) * 1024 + t0] = o;
        } else {
#pragma unroll
          for (int r = 0; r < 4; r++)
            ((unsigned short*)C)[(size_t)(row0 + r) * N + col] = f2bf(v[r]);
        }
      }
  }
}

// ---------------------------------------------------------------------------
// attn pass A (standalone, k-split 2x): l-sums only.  4-wave, grid 1024,
// 4 blocks/CU (round-13/15 verified form).  Grid: bid&31 = (b,h) pair,
// (bid>>5)&15 = qt, bid>>9 = k-half.  LDS = sK only (32 KB).
// s_setprio around MFMA (T5).
// ---------------------------------------------------------------------------
__global__ __launch_bounds__(256, 4) void attn_a(
    const unsigned short* __restrict__ Qg, const unsigned short* __restrict__ Kg,
    float* __restrict__ Lws)
{
  __shared__ unsigned short sK[2][2][64][64];   // [buf][stream]

  const int pair = blockIdx.x & 31;           // h = pair&7 -> XCD L2 affinity
  const int b = pair >> 3, h = pair & 7;
  const int qt = (blockIdx.x >> 5) & 15;
  const int kh = blockIdx.x >> 9;             // k-half 0/1
  const int tid = threadIdx.x;
  const int lane = tid & 63, wave = tid >> 6;
  const int l15 = lane & 15, quad = lane >> 4, swl = l15 & 7;
  const int lrow = lane >> 3;
  const int lc8 = ((lane & 7) ^ (lrow & 7)) * 8;
  const int qbase = qt * 64 + wave * 16;
  const float S2 = 0.125f * 1.44269504f;      // scale * log2(e)

  const unsigned short* kgp[2];
#pragma unroll
  for (int st = 0; st < 2; st++)
    kgp[st] = Kg + (size_t)((b * 2 + st) * 1024) * 512 + h * 64;

  // Q fragments, both directions
  v8bf qf[2][2];
#pragma unroll
  for (int d = 0; d < 2; d++)
#pragma unroll
    for (int s = 0; s < 2; s++) {
      int qrow = (b * 2 + d) * 1024 + qbase + l15;
      qf[d][s] = ldfrag(&Qg[(size_t)qrow * 512 + h * 64 + s * 32 + quad * 8]);
    }

  const unsigned short* gA[4];
  unsigned short* lA[2][4];
#pragma unroll
  for (int t = 0; t < 4; t++) {
    int c = wave * 4 + t;                     // 16 K chunks over 4 waves
    gA[t] = kgp[c >> 3] + (size_t)((c & 7) * 8 + lrow) * 512 + lc8
            + (size_t)kh * 262144;            // k-half base (8 tiles)
    lA[0][t] = &sK[0][c >> 3][(c & 7) * 8][0];
    lA[1][t] = &sK[1][c >> 3][(c & 7) * 8][0];
  }

  float lacc[2] = {0.f, 0.f};
#pragma unroll
  for (int t = 0; t < 4; t++) g2l(gA[t], lA[0][t]);      // tile 0

  for (int kt = 0; kt < 8; kt++) {
    drain_vmem();                             // tile kt DMA landed
    __syncthreads();
    if (kt < 7) {
#pragma unroll
      for (int t = 0; t < 4; t++)
        g2l(gA[t] + (size_t)(kt + 1) * 32768, lA[(kt + 1) & 1][t]);
    }
    const int bu = kt & 1;
    v4f acc[2][4] = {};
    __builtin_amdgcn_s_setprio(1);
#pragma unroll
    for (int s = 0; s < 2; s++)
#pragma unroll
      for (int d = 0; d < 2; d++)
#pragma unroll
        for (int j = 0; j < 4; j++) {
          v8bf kf = ldfrag(&sK[bu][1 - d][j * 16 + l15][((s * 4 + quad) ^ swl) * 8]);
          acc[d][j] = MFMA32(kf, qf[d][s], acc[d][j]);
        }
    __builtin_amdgcn_s_setprio(0);
#pragma unroll
    for (int d = 0; d < 2; d++)
#pragma unroll
      for (int j = 0; j < 4; j++)
#pragma unroll
        for (int r = 0; r < 4; r++)
          lacc[d] += fexp2(acc[d][j][r] * S2);
  }

  float lv[2];
#pragma unroll
  for (int d = 0; d < 2; d++) {
    float v = lacc[d];
    v += __shfl_xor(v, 16);
    v += __shfl_xor(v, 32);
    lv[d] = v;                                // partial row-sum (linear domain)
  }
  if (quad == 0) {
#pragma unroll
    for (int d = 0; d < 2; d++) {
      int qrow = (b * 2 + d) * 1024 + qbase + l15;
      Lws[(size_t)qrow * 2 + kh] = lv[d];
    }
  }
}

// ---------------------------------------------------------------------------
// attn pass B: combine + PV.  8-wave qt-merge (round 13) + 2-TILES-PER-
// BARRIER: 4 LDS slots (128 KB), barrier count 16 -> 8, per-wave compute per
// barrier period doubles (the amortization lever round 1 proved, applied in
// the winning direction).  attn_b runs 1 block/CU in lockstep, so barrier
// pacing has no inter-block TLP to hide it.  Slot addressing is a flat
// +8192-elem stride off the slot-0 pointers (no runtime-indexed private
// arrays -> no scratch, rule #20).  Issue slots are disjoint from compute
// slots each iteration (it: compute (2it)&3,(2it+1)&3; issue (2it+2)&3,
// (2it+3)&3; freed pre-barrier).  Same drain->barrier->issue->compute
// protocol as all verified kernels.  s_setprio around MFMA clusters (T5).
// ---------------------------------------------------------------------------
__global__ __launch_bounds__(512, 1) void attn_b(
    const unsigned short* __restrict__ Qg, const unsigned short* __restrict__ Kg,
    const unsigned short* __restrict__ VTg, const float* __restrict__ Lws,
    unsigned short* __restrict__ Hc)
{
  __shared__ unsigned short sK[4][2][64][64];   // [slot][stream]  64 KB
  __shared__ unsigned short sV[4][2][64][64];   // [slot][stream]  64 KB

  const int pair = blockIdx.x & 31;           // h = pair&7 -> XCD L2 affinity
  const int b = pair >> 3, h = pair & 7;
  const int qt = blockIdx.x >> 5;             // 0..7 (128 q-rows per block)
  const int tid = threadIdx.x;
  const int lane = tid & 63, wave = tid >> 6; // 0..7
  const int l15 = lane & 15, quad = lane >> 4, swl = l15 & 7;
  const int lrow = lane >> 3;
  const int lc8 = ((lane & 7) ^ (lrow & 7)) * 8;
  const int qbase = qt * 128 + wave * 16;
  const float S2 = 0.125f * 1.44269504f;      // scale * log2(e)

  const unsigned short* kgp[2];
  const unsigned short* vgp[2];
#pragma unroll
  for (int st = 0; st < 2; st++) {
    kgp[st] = Kg + (size_t)((b * 2 + st) * 1024) * 512 + h * 64;
    vgp[st] = VTg + (size_t)(((b * 2 + st) * 8 + h) * 64) * 1024;
  }

  // Q fragments, both directions
  v8bf qf[2][2];
#pragma unroll
  for (int d = 0; d < 2; d++)
#pragma unroll
    for (int s = 0; s < 2; s++) {
      int qrow = (b * 2 + d) * 1024 + qbase + l15;
      qf[d][s] = ldfrag(&Qg[(size_t)qrow * 512 + h * 64 + s * 32 + quad * 8]);
    }

  // l-sums: add the two k-half partials, then log2
  float ll[2];
#pragma unroll
  for (int d = 0; d < 2; d++) {
    int qrow = (b * 2 + d) * 1024 + qbase + l15;
    float2 p = *(const float2*)&Lws[(size_t)qrow * 2];
    ll[d] = __log2f(p.x + p.y);
  }
  const float dll = ll[0] - ll[1];

  v4f oacc[2][4] = {};
  {
    const unsigned short* gB[4];
    unsigned short* lB0[4];                   // slot-0 staging destinations
    size_t stp[4];
#pragma unroll
    for (int t = 0; t < 4; t++) {
      int c = wave * 4 + t;                   // 16 K + 16 V chunks over 8 waves
      if (c < 16) {
        gB[t] = kgp[c >> 3] + (size_t)((c & 7) * 8 + lrow) * 512 + lc8;
        stp[t] = 32768;
        lB0[t] = &sK[0][c >> 3][(c & 7) * 8][0];
      } else {
        int cv = c - 16;
        gB[t] = vgp[cv >> 3] + (size_t)((cv & 7) * 8 + lrow) * 1024 + lc8;
        stp[t] = 64;
        lB0[t] = &sV[0][cv >> 3][(cv & 7) * 8][0];
      }
    }
    // prologue: tile 0 -> slot 0, tile 1 -> slot 1  (slot stride 8192 elems)
#pragma unroll
    for (int t = 0; t < 4; t++) g2l(gB[t], lB0[t]);
#pragma unroll
    for (int t = 0; t < 4; t++) g2l(gB[t] + stp[t], lB0[t] + 8192);

    for (int it = 0; it < 8; it++) {
      drain_vmem();                           // tiles 2it, 2it+1 landed
      __syncthreads();                        // visible to all waves
      if (it < 7) {
        const int k2 = 2 * it + 2, k3 = 2 * it + 3;
#pragma unroll
        for (int t = 0; t < 4; t++)
          g2l(gB[t] + (size_t)k2 * stp[t], lB0[t] + (k2 & 3) * 8192);
#pragma unroll
        for (int t = 0; t < 4; t++)
          g2l(gB[t] + (size_t)k3 * stp[t], lB0[t] + (k3 & 3) * 8192);
      }

#pragma unroll
      for (int half = 0; half < 2; half++) {
        const int kt = 2 * it + half;
        const int sl = kt & 3;

        v4f acc[2][4] = {};
        __builtin_amdgcn_s_setprio(1);
#pragma unroll
        for (int s = 0; s < 2; s++)
#pragma unroll
          for (int d = 0; d < 2; d++)
#pragma unroll
            for (int j = 0; j < 4; j++) {
              v8bf kf = ldfrag(&sK[sl][1 - d][j * 16 + l15][((s * 4 + quad) ^ swl) * 8]);
              acc[d][j] = MFMA32(kf, qf[d][s], acc[d][j]);
            }
        __builtin_amdgcn_s_setprio(0);

#pragma unroll
        for (int j = 0; j < 4; j++) {
          float r0[4], r1[4];
#pragma unroll
          for (int r = 0; r < 4; r++) {
            float t = fmaf(acc[1][j][r] - acc[0][j][r], S2, dll);
            float ri = __builtin_amdgcn_rcpf(1.f + fexp2(t));
            r0[r] = ri;
            r1[r] = 1.f - ri;
          }
#if HAVE_MFMA16
          uint2 w0, w1;
          w0.x = pkbf(r0[0], r0[1]); w0.y = pkbf(r0[2], r0[3]);
          w1.x = pkbf(r1[0], r1[1]); w1.y = pkbf(r1[2], r1[3]);
          v4s af0 = __builtin_bit_cast(v4s, w0);
          v4s af1 = __builtin_bit_cast(v4s, w1);
          int vcol = ((j * 2 + (quad >> 1)) ^ swl) * 8 + (quad & 1) * 4;
          __builtin_amdgcn_s_setprio(1);
#pragma unroll
          for (int nt = 0; nt < 4; nt++) {
            v4s vf0 = ld4s(&sV[sl][1][nt * 16 + l15][vcol]);
            v4s vf1 = ld4s(&sV[sl][0][nt * 16 + l15][vcol]);
            oacc[0][nt] = MFMA16(af0, vf0, oacc[0][nt]);
            oacc[1][nt] = MFMA16(af1, vf1, oacc[1][nt]);
          }
          __builtin_amdgcn_s_setprio(0);
#else
#pragma unroll
          for (int d = 0; d < 2; d++) {
            float (&cb)[4] = (d == 0) ? r0 : r1;
            v8bf a;
#pragma unroll
            for (int jj = 0; jj < 8; jj++) {
              int src = l15 + 16 * ((jj >> 2) + (quad & 1) * 2);
              float v = __shfl(cb[jj & 3], src);
              a[jj] = __builtin_bit_cast(__bf16, f2bf(v));
            }
#pragma unroll
            for (int nt = 0; nt < 4; nt++) {
              v8bf vf = ldfrag(&sV[sl][1 - d][nt * 16 + l15]
                                 [(((j & 2) * 2 + quad) ^ swl) * 8]);
              oacc[d][nt] = MFMA32(a, vf, oacc[d][nt]);
            }
          }
#endif
        }
      }
    }
  }

#pragma unroll
  for (int d = 0; d < 2; d++)
#pragma unroll
    for (int nt = 0; nt < 4; nt++)
#pragma unroll
      for (int r = 0; r < 4; r++) {
        int row = (b * 2 + d) * 1024 + qbase + quad * 4 + r;
        int col = h * 64 + nt * 16 + l15;
        Hc[(size_t)row * 512 + col] = f2bf(oacc[d][nt][r]);
      }
}

// ---------------------------------------------------------------------------
// LayerNorm (over D=512) + gate + residual.  One WAVE per row (no LDS).
// ---------------------------------------------------------------------------
__global__ __launch_bounds__(256) void ln_kernel(
    const unsigned short* __restrict__ Pb, const float* __restrict__ hidden,
    const float* __restrict__ ln_g, const float* __restrict__ ln_b,
    const float* __restrict__ gate, float* __restrict__ out)
{
  const int row = blockIdx.x * 4 + (threadIdx.x >> 6);
  const int s = (row >> 10) & 1;
  const int lane = threadIdx.x & 63;
  const int d0 = lane * 8;

  uint4 up = *(const uint4*)&Pb[(size_t)row * 512 + d0];
  float x[8] = { lo2f(up.x), hi2f(up.x), lo2f(up.y), hi2f(up.y),
                 lo2f(up.z), hi2f(up.z), lo2f(up.w), hi2f(up.w) };
  float s1 = 0.f, s2 = 0.f;
#pragma unroll
  for (int i = 0; i < 8; i++) { s1 += x[i]; s2 += x[i] * x[i]; }
#pragma unroll
  for (int m = 1; m < 64; m <<= 1) { s1 += __shfl_xor(s1, m); s2 += __shfl_xor(s2, m); }
  float mu = s1 * (1.f / 512.f);
  float var = s2 * (1.f / 512.f) - mu * mu;
  float rs = rsqrtf(var + 1e-5f);
  float al = gate[s];

  float4 h0 = *(const float4*)&hidden[(size_t)row * 512 + d0];
  float4 h1 = *(const float4*)&hidden[(size_t)row * 512 + d0 + 4];
  float4 g0 = *(const float4*)&ln_g[s * 512 + d0];
  float4 g1 = *(const float4*)&ln_g[s * 512 + d0 + 4];
  float4 bb0 = *(const float4*)&ln_b[s * 512 + d0];
  float4 bb1 = *(const float4*)&ln_b[s * 512 + d0 + 4];
  float4 o0, o1;
  o0.x = h0.x + ((x[0] - mu) * rs * g0.x + bb0.x) * al;
  o0.y = h0.y + ((x[1] - mu) * rs * g0.y + bb0.y) * al;
  o0.z = h0.z + ((x[2] - mu) * rs * g0.z + bb0.z) * al;
  o0.w = h0.w + ((x[3] - mu) * rs * g0.w + bb0.w) * al;
  o1.x = h1.x + ((x[4] - mu) * rs * g1.x + bb1.x) * al;
  o1.y = h1.y + ((x[5] - mu) * rs * g1.y + bb1.y) * al;
  o1.z = h1.z + ((x[6] - mu) * rs * g1.z + bb1.z) * al;
  o1.w = h1.w + ((x[7] - mu) * rs * g1.w + bb1.w) * al;
  *(float4*)&out[(size_t)row * 512 + d0] = o0;
  *(float4*)&out[(size_t)row * 512 + d0 + 4] = o1;
}

// ---------------------------------------------------------------------------
extern "C" void kernel_launch(void* const* d_in, const int* in_sizes, int n_in,
                              void* d_out, int out_size, void* d_ws, size_t ws_size,
                              hipStream_t stream)
{
  const float* hidden = (const float*)d_in[0];
  const float* Wq = (const float*)d_in[1];
  const float* bq = (const float*)d_in[2];
  const float* Wk = (const float*)d_in[3];
  const float* bk = (const float*)d_in[4];
  const float* Wv = (const float*)d_in[5];
  const float* bv = (const float*)d_in[6];
  const float* Wo = (const float*)d_in[7];
  const float* bo = (const float*)d_in[8];
  const float* ln_g = (const float*)d_in[9];
  const float* ln_b = (const float*)d_in[10];
  const float* gate = (const float*)d_in[11];

  unsigned short* U = (unsigned short*)d_ws;
  unsigned short* Xbf = U;
  unsigned short* Wqb = U + 4194304;
  unsigned short* Wkb = U + 4456448;
  unsigned short* Wvb = U + 4718592;
  unsigned short* Wob = U + 4980736;
  unsigned short* Qg  = U + 5242880;
  unsigned short* Kg  = U + 9437184;
  unsigned short* VT  = U + 13631488;
  unsigned short* Hc  = U + 17825792;
  unsigned short* Pb  = (unsigned short*)((char*)d_ws + 44302336);
  float* Lws = (float*)d_ws;                  // overlays Xbf (dead after gemm1)

  convert_kernel<<<dim3(5120), 256, 0, stream>>>(hidden, Wq, Wk, Wv, Wo, Xbf);
  gemm_bt<0, 128><<<dim3(4, 64, 3), 256, 0, stream>>>(Xbf, Wqb, Wkb, Wvb, bq, bk, bv, Qg, Kg, VT);
  attn_a<<<dim3(1024), 256, 0, stream>>>(Qg, Kg, Lws);
  attn_b<<<dim3(256), 512, 0, stream>>>(Qg, Kg, VT, Lws, Hc);
  gemm_bt<0, 64><<<dim3(4, 128, 1), 256, 0, stream>>>(Hc, Wob, Wob, Wob, bo, bo, bo, Pb, Pb, Pb);
  ln_kernel<<<dim3(2048), 256, 0, stream>>>(Pb, hidden, ln_g, ln_b, gate, (float*)d_out);
}